// Round 2
// baseline (359.075 us; speedup 1.0000x reference)
//
#include <hip/hip_runtime.h>
#include <hip/hip_bf16.h>
#include <math.h>

// Problem constants
#define BATCH 64
#define CIN   32
#define TIN   2048
#define FILT  64
#define WIN   5
#define TP1   2044   // conv1 out
#define TP2   2040   // pool out
#define LOUT  2036   // conv2 out
#define DEMB  256
#define DA    64
#define NSEC  11
#define NC    4      // S chunks
#define CS    509    // l's per chunk (4*509 = 2036)
#define TILE_T 252   // h2 outputs per conv1 block

// ---------------------------------------------------------------------------
// Kernel A: conv1 + bias + maxpool(5,1) + BN partial sums. (unchanged R1)
// ---------------------------------------------------------------------------
__global__ __launch_bounds__(256) void k_conv1pool(
    const float* __restrict__ x, const float* __restrict__ w1,
    const float* __restrict__ b1, float* __restrict__ h2,
    float* __restrict__ bnps, float* __restrict__ bnpq) {
  __shared__ float xl[CIN * 264];
  const int b   = blockIdx.y;
  const int t0  = blockIdx.x * TILE_T;
  const int tid = threadIdx.x;

  for (int i = tid; i < CIN * 264; i += 256) {
    int c = i / 264, o = i - c * 264;
    int gt = t0 + o;
    float v = 0.f;
    if (o < 260 && gt < TIN) v = x[(b * CIN + c) * TIN + gt];
    xl[i] = v;
  }
  __syncthreads();

  const int tg  = tid & 63;
  const int tb  = tg * 4;
  const int wf0 = __builtin_amdgcn_readfirstlane(tid >> 6) * 16;  // wave-uniform
  const float* wb = w1 + wf0 * (CIN * WIN);

  float acc[16][4];
#pragma unroll
  for (int ff = 0; ff < 16; ++ff) {
    float bias = b1[wf0 + ff];
    acc[ff][0] = bias; acc[ff][1] = bias; acc[ff][2] = bias; acc[ff][3] = bias;
  }

  for (int c = 0; c < CIN; ++c) {
    float4 xa  = *(const float4*)&xl[c * 264 + tb];
    float4 xb4 = *(const float4*)&xl[c * 264 + tb + 4];
    float xw[8] = {xa.x, xa.y, xa.z, xa.w, xb4.x, xb4.y, xb4.z, xb4.w};
#pragma unroll
    for (int ff = 0; ff < 16; ++ff) {
      const float* wr = wb + ff * (CIN * WIN) + c * WIN;   // uniform -> s_load
#pragma unroll
      for (int k = 0; k < WIN; ++k) {
        float wv = wr[k];
        acc[ff][0] = fmaf(xw[k + 0], wv, acc[ff][0]);
        acc[ff][1] = fmaf(xw[k + 1], wv, acc[ff][1]);
        acc[ff][2] = fmaf(xw[k + 2], wv, acc[ff][2]);
        acc[ff][3] = fmaf(xw[k + 3], wv, acc[ff][3]);
      }
    }
  }

  const bool rowvalid = (tg < 63);
  const int blk = blockIdx.y * 9 + blockIdx.x;
#pragma unroll
  for (int ff = 0; ff < 16; ++ff) {
    float n0 = __shfl_down(acc[ff][0], 1);
    float n1 = __shfl_down(acc[ff][1], 1);
    float n2 = __shfl_down(acc[ff][2], 1);
    float n3 = __shfl_down(acc[ff][3], 1);
    float h[8] = {acc[ff][0], acc[ff][1], acc[ff][2], acc[ff][3], n0, n1, n2, n3};
    float o0 = fmaxf(fmaxf(fmaxf(h[0], h[1]), fmaxf(h[2], h[3])), h[4]);
    float o1 = fmaxf(fmaxf(fmaxf(h[1], h[2]), fmaxf(h[3], h[4])), h[5]);
    float o2 = fmaxf(fmaxf(fmaxf(h[2], h[3]), fmaxf(h[4], h[5])), h[6]);
    float o3 = fmaxf(fmaxf(fmaxf(h[3], h[4]), fmaxf(h[5], h[6])), h[7]);
    const int f = wf0 + ff;
    float s = 0.f, q = 0.f;
    const int t2b = t0 + tb;
    if (rowvalid && (t2b + 3 < TP2)) {
      *(float4*)&h2[(b * FILT + f) * TP2 + t2b] = make_float4(o0, o1, o2, o3);
      s = o0 + o1 + o2 + o3;
      q = o0 * o0 + o1 * o1 + o2 * o2 + o3 * o3;
    } else if (rowvalid) {
      float ov[4] = {o0, o1, o2, o3};
#pragma unroll
      for (int j = 0; j < 4; ++j) {
        int t2 = t2b + j;
        if (t2 < TP2) { h2[(b * FILT + f) * TP2 + t2] = ov[j]; s += ov[j]; q += ov[j] * ov[j]; }
      }
    }
#pragma unroll
    for (int off = 32; off > 0; off >>= 1) {
      s += __shfl_down(s, off);
      q += __shfl_down(q, off);
    }
    if (tg == 0) { bnps[blk * FILT + f] = s; bnpq[blk * FILT + f] = q; }
  }
}

// ---------------------------------------------------------------------------
// Kernel B: BN finalize + fold into conv2 weights — FP64 (rsqrtf's ~1e-5 rel
// error alone caused ~50 bucket flips in R1). ws2/c0 carried as double.
// ---------------------------------------------------------------------------
__global__ void k_bnfin(const float* __restrict__ bnps, const float* __restrict__ bnpq,
                        const float* __restrict__ gamma, const float* __restrict__ beta,
                        const float* __restrict__ w2, const float* __restrict__ b2,
                        double* __restrict__ ws2, double* __restrict__ c0p) {
  const int f = threadIdx.x;  // 0..63
  double s = 0.0, q = 0.0;
  for (int blk = 0; blk < 576; ++blk) {
    s += (double)bnps[blk * FILT + f];
    q += (double)bnpq[blk * FILT + f];
  }
  const double N = (double)(BATCH * TP2);
  double mu  = s / N;
  double var = q / N - mu * mu;
  double sc  = (double)gamma[f] / sqrt(var + 1e-5);
  double sh  = (double)beta[f] - mu * sc;
  double wsum = 0.0;
#pragma unroll
  for (int k = 0; k < WIN; ++k) {
    double wv = (double)w2[f * WIN + k];
    ws2[f * WIN + k] = sc * wv;
    wsum += wv;
  }
  double part = sh * wsum;
#pragma unroll
  for (int off = 32; off > 0; off >>= 1) part += __shfl_down(part, off);
  if (f == 0) c0p[0] = part + (double)b2[0];
}

// ---------------------------------------------------------------------------
// Kernel C: conv2 in FP64 accumulation + FP64 sigmoid/quantize + histogram.
// ---------------------------------------------------------------------------
__global__ __launch_bounds__(256) void k_conv2(
    const float* __restrict__ h2, const double* __restrict__ ws2,
    const double* __restrict__ c0p, int* __restrict__ idxp, int* __restrict__ count) {
  __shared__ float hl[FILT * 260];
  __shared__ int hist[DEMB];
  const int b = blockIdx.y;
  const int t0 = blockIdx.x * 256;
  const int tid = threadIdx.x;
  for (int i = tid; i < FILT * 260; i += 256) {
    int f = i / 260, o = i - f * 260;
    int gt = t0 + o;
    hl[i] = (gt < TP2) ? h2[(b * FILT + f) * TP2 + gt] : 0.f;
  }
  hist[tid] = 0;
  __syncthreads();
  const int t = t0 + tid;
  if (t < LOUT) {
    double z = c0p[0];
    for (int f = 0; f < FILT; ++f) {
      const double* wr = ws2 + f * WIN;
      z = fma((double)hl[f * 260 + tid + 0], wr[0], z);
      z = fma((double)hl[f * 260 + tid + 1], wr[1], z);
      z = fma((double)hl[f * 260 + tid + 2], wr[2], z);
      z = fma((double)hl[f * 260 + tid + 3], wr[3], z);
      z = fma((double)hl[f * 260 + tid + 4], wr[4], z);
    }
    z = z > 0.0 ? z : 0.0;
    double c = 1.0 / (1.0 + exp(-z));
    int iv = (int)ceil(c * 256.0) - 1;
    iv = min(max(iv, 0), DEMB - 1);
    idxp[b * LOUT + t] = iv;
    atomicAdd(&hist[iv], 1);
  }
  __syncthreads();
  atomicAdd(&count[b * DEMB + tid], hist[tid]);
}

// ---------------------------------------------------------------------------
// Transpose helpers (one-time small)
// ---------------------------------------------------------------------------
__global__ void k_t1(const float* __restrict__ W1, float* __restrict__ W1T) {
  int i = blockIdx.x * 256 + threadIdx.x;   // 509*256 == 130304 exactly
  int l = i >> 6, a = i & 63;
  W1T[i] = W1[a * LOUT + l];
}
__global__ void k_t2(const float* __restrict__ emb, float* __restrict__ embT) {
  int i = blockIdx.x * 256 + threadIdx.x;   // 65536
  int d = i >> 8, j = i & 255;
  embT[i] = emb[j * DEMB + d];
}

// ---------------------------------------------------------------------------
// Kernel D: S[b,a,j] = sum_{l in chunk: idx[b,l]==j} W1[a,l]. (unchanged R1)
// ---------------------------------------------------------------------------
__global__ __launch_bounds__(256) void k_sbuild(
    const int* __restrict__ idxp, const float* __restrict__ w1t,
    float* __restrict__ Sg) {
  __shared__ float S[DA * 257];
  __shared__ int il[512];
  const int b = blockIdx.y, ch = blockIdx.x;
  const int tid = threadIdx.x;
  for (int i = tid; i < DA * 257; i += 256) S[i] = 0.f;
  const int l0 = ch * CS;
  for (int i = tid; i < CS; i += 256) il[i] = idxp[b * LOUT + l0 + i];
  __syncthreads();
  const int a = tid & 63, w = tid >> 6;
#pragma unroll 4
  for (int li = w; li < CS; li += 4) {
    int j = il[li];                          // wave-uniform broadcast
    float v = w1t[(l0 + li) * DA + a];       // coalesced 256B/wave
    atomicAdd(&S[a * 257 + j], v);
  }
  __syncthreads();
  for (int i = tid; i < DA * DEMB; i += 256) {
    int aa = i >> 8, j = i & 255;
    Sg[((b * NC + ch) * DA + aa) * DEMB + j] = S[aa * 257 + j];
  }
}

// ---------------------------------------------------------------------------
// Kernel E: fp32 GEMM T = (sum_ch S) @ emb256, epilogue A = sum_a W2 tanh(T).
// ---------------------------------------------------------------------------
__global__ __launch_bounds__(256) void k_gemmA(
    const float* __restrict__ Sg, const float* __restrict__ emb,
    const float* __restrict__ W2, float* __restrict__ Avec) {
  __shared__ float Al[16 * 64];
  __shared__ float Bl[16 * 64];
  __shared__ float red[16 * 64];
  const int b = blockIdx.x, c0 = blockIdx.y * 64;
  const int tid = threadIdx.x;
  const int tx = tid & 15, ty = tid >> 4;
  const int sa = tid >> 2, skq = (tid & 3) * 4;   // A staging map
  const int bk = tid >> 4, bseg = tid & 15;       // B staging map
  float acc[4][4] = {{0}};

  for (int kc = 0; kc < 16; ++kc) {
    const int kb = kc * 16;
    float4 v0 = *(const float4*)&Sg[((b * NC + 0) * DA + sa) * DEMB + kb + skq];
    float4 v1 = *(const float4*)&Sg[((b * NC + 1) * DA + sa) * DEMB + kb + skq];
    float4 v2 = *(const float4*)&Sg[((b * NC + 2) * DA + sa) * DEMB + kb + skq];
    float4 v3 = *(const float4*)&Sg[((b * NC + 3) * DA + sa) * DEMB + kb + skq];
    float4 sv = make_float4(v0.x + v1.x + v2.x + v3.x, v0.y + v1.y + v2.y + v3.y,
                            v0.z + v1.z + v2.z + v3.z, v0.w + v1.w + v2.w + v3.w);
    Al[(skq + 0) * 64 + sa] = sv.x;
    Al[(skq + 1) * 64 + sa] = sv.y;
    Al[(skq + 2) * 64 + sa] = sv.z;
    Al[(skq + 3) * 64 + sa] = sv.w;
    float4 e4 = *(const float4*)&emb[(kb + bk) * DEMB + c0 + bseg * 4];
    *(float4*)&Bl[bk * 64 + bseg * 4] = e4;
    __syncthreads();
#pragma unroll
    for (int k = 0; k < 16; ++k) {
      float4 av = *(const float4*)&Al[k * 64 + ty * 4];
      float4 bv = *(const float4*)&Bl[k * 64 + tx * 4];
      acc[0][0] = fmaf(av.x, bv.x, acc[0][0]); acc[0][1] = fmaf(av.x, bv.y, acc[0][1]);
      acc[0][2] = fmaf(av.x, bv.z, acc[0][2]); acc[0][3] = fmaf(av.x, bv.w, acc[0][3]);
      acc[1][0] = fmaf(av.y, bv.x, acc[1][0]); acc[1][1] = fmaf(av.y, bv.y, acc[1][1]);
      acc[1][2] = fmaf(av.y, bv.z, acc[1][2]); acc[1][3] = fmaf(av.y, bv.w, acc[1][3]);
      acc[2][0] = fmaf(av.z, bv.x, acc[2][0]); acc[2][1] = fmaf(av.z, bv.y, acc[2][1]);
      acc[2][2] = fmaf(av.z, bv.z, acc[2][2]); acc[2][3] = fmaf(av.z, bv.w, acc[2][3]);
      acc[3][0] = fmaf(av.w, bv.x, acc[3][0]); acc[3][1] = fmaf(av.w, bv.y, acc[3][1]);
      acc[3][2] = fmaf(av.w, bv.z, acc[3][2]); acc[3][3] = fmaf(av.w, bv.w, acc[3][3]);
    }
    __syncthreads();
  }
  float cs[4] = {0.f, 0.f, 0.f, 0.f};
#pragma unroll
  for (int r = 0; r < 4; ++r) {
    float wv = W2[ty * 4 + r];
#pragma unroll
    for (int j = 0; j < 4; ++j) cs[j] += tanhf(acc[r][j]) * wv;
  }
#pragma unroll
  for (int j = 0; j < 4; ++j) red[ty * 64 + tx * 4 + j] = cs[j];
  __syncthreads();
  if (tid < 64) {
    float s = 0.f;
#pragma unroll
    for (int q = 0; q < 16; ++q) s += red[q * 64 + tid];
    Avec[b * DEMB + c0 + tid] = s;
  }
}

// ---------------------------------------------------------------------------
// Kernel G: bucket softmax + scores. (unchanged R1)
// ---------------------------------------------------------------------------
__global__ __launch_bounds__(256) void k_att(
    const float* __restrict__ Avec, const float* __restrict__ embT,
    const int* __restrict__ count, const float* __restrict__ linw,
    const float* __restrict__ linb, float* __restrict__ p,
    float* __restrict__ scores) {
  __shared__ float Al[DEMB];
  __shared__ float scratch[4];
  const int b = blockIdx.x, j = threadIdx.x;
  Al[j] = Avec[b * DEMB + j];
  __syncthreads();
  float dot = 0.f;
  for (int d = 0; d < DEMB; ++d) dot = fmaf(embT[d * DEMB + j], Al[d], dot);
  const int cnt = count[b * DEMB + j];
  float v = (cnt > 0) ? dot : -3.4e38f;
#pragma unroll
  for (int off = 32; off > 0; off >>= 1) v = fmaxf(v, __shfl_down(v, off));
  if ((j & 63) == 0) scratch[j >> 6] = v;
  __syncthreads();
  const float m = fmaxf(fmaxf(scratch[0], scratch[1]), fmaxf(scratch[2], scratch[3]));
  __syncthreads();
  float e = (cnt > 0) ? expf(dot - m) : 0.f;
  float zs = e * (float)cnt;
#pragma unroll
  for (int off = 32; off > 0; off >>= 1) zs += __shfl_down(zs, off);
  if ((j & 63) == 0) scratch[j >> 6] = zs;
  __syncthreads();
  const float Z = scratch[0] + scratch[1] + scratch[2] + scratch[3];
  p[b * DEMB + j] = (cnt > 0) ? e / Z : 0.f;
  for (int s = 0; s < NSEC; ++s) {
    __syncthreads();
    float part = Al[j] * linw[s * DEMB + j];
#pragma unroll
    for (int off = 32; off > 0; off >>= 1) part += __shfl_down(part, off);
    if ((j & 63) == 0) scratch[j >> 6] = part;
    __syncthreads();
    if (j == 0)
      scores[b * NSEC + s] = scratch[0] + scratch[1] + scratch[2] + scratch[3] + linb[s];
  }
}

// ---------------------------------------------------------------------------
// Kernel H: att[b,l] = p[b, idx[b,l]]
// ---------------------------------------------------------------------------
__global__ void k_gather(const int* __restrict__ idxp, const float* __restrict__ p,
                         float* __restrict__ att) {
  const int b = blockIdx.y;
  const int t = blockIdx.x * 256 + threadIdx.x;
  if (t < LOUT) att[b * LOUT + t] = p[b * DEMB + idxp[b * LOUT + t]];
}

// ---------------------------------------------------------------------------
extern "C" void kernel_launch(void* const* d_in, const int* in_sizes, int n_in,
                              void* d_out, int out_size, void* d_ws, size_t ws_size,
                              hipStream_t stream) {
  const float* x      = (const float*)d_in[0];
  const float* w1     = (const float*)d_in[1];
  const float* b1     = (const float*)d_in[2];
  const float* gamma  = (const float*)d_in[3];
  const float* beta   = (const float*)d_in[4];
  const float* w2     = (const float*)d_in[5];
  const float* b2     = (const float*)d_in[6];
  const float* emb    = (const float*)d_in[7];
  const float* W1     = (const float*)d_in[8];
  const float* W2     = (const float*)d_in[9];
  const float* linw   = (const float*)d_in[10];
  const float* linb   = (const float*)d_in[11];

  char* ws = (char*)d_ws;
  // layout (bytes)
  int*    count = (int*)   (ws + 0);           // 65536
  double* ws2   = (double*)(ws + 65536);       // 320 d -> ends 68096
  double* c0p   = (double*)(ws + 68096);       // 1 d   -> pad to 68608
  float*  bnps  = (float*) (ws + 68608);       // 576*64 f -> 216064
  float*  bnpq  = (float*) (ws + 216064);      // -> 363520
  int*    idxp  = (int*)   (ws + 363520);      // 64*2036 -> 884736
  float*  w1t   = (float*) (ws + 884736);      // 2036*64 -> 1405952
  float*  embT  = (float*) (ws + 1405952);     // 256*256 -> 1668096
  float*  Avec  = (float*) (ws + 1668096);     // 64*256 -> 1733632
  float*  p     = (float*) (ws + 1733632);     // 64*256 -> 1799168
  float*  h2    = (float*) (ws + 1799168);     // 64*64*2040 -> 35222528
  float*  Sg    = (float*) (ws + 35222528);    // 4*64*64*256 -> 51999744

  float* att_out    = (float*)d_out;
  float* scores_out = (float*)d_out + BATCH * LOUT;

  hipMemsetAsync(count, 0, 65536, stream);
  k_t1<<<dim3(509), 256, 0, stream>>>(W1, w1t);
  k_t2<<<dim3(256), 256, 0, stream>>>(emb, embT);
  k_conv1pool<<<dim3(9, 64), 256, 0, stream>>>(x, w1, b1, h2, bnps, bnpq);
  k_bnfin<<<dim3(1), 64, 0, stream>>>(bnps, bnpq, gamma, beta, w2, b2, ws2, c0p);
  k_conv2<<<dim3(8, 64), 256, 0, stream>>>(h2, ws2, c0p, idxp, count);
  k_sbuild<<<dim3(NC, 64), 256, 0, stream>>>(idxp, w1t, Sg);
  k_gemmA<<<dim3(64, 4), 256, 0, stream>>>(Sg, emb, W2, Avec);
  k_att<<<dim3(64), 256, 0, stream>>>(Avec, embT, count, linw, linb, p, scores_out);
  k_gather<<<dim3(8, 64), 256, 0, stream>>>(idxp, p, att_out);
}